// Round 7
// baseline (265.553 us; speedup 1.0000x reference)
//
#include <hip/hip_runtime.h>

#define NN 50000
#define NE 800000
#define FD 128
#define KH 384
#define NU 256
#define NG 64
#define MAXDEG 64
#define NB 98          // dst buckets of 512 nodes
#define BCAP 10240     // per-bucket capacity
#define EPB 4096       // edges per k_bin block
#define TM 32          // gsom rows per tile
#define NT 1564        // 50048 / 32

typedef __attribute__((__ext_vector_type__(8))) short short8;
typedef __attribute__((__ext_vector_type__(4))) float f32x4;
typedef __attribute__((__ext_vector_type__(2))) float f32x2;
typedef __attribute__((__ext_vector_type__(2))) long long2v;

// ---- ws layout (bytes, 16B-aligned) ----
#define OFF_POS   0u           // NB int (+pad)         512     [memset]
#define OFF_G     512u         // 64*256 f32            65536   [memset]
#define OFF_CNT   66048u       // 50048 int             200192
#define OFF_BE    266240u      // NB*BCAP u32           4014080
#define OFF_COL   4280320u     // 50048*64 u16          6406144
#define OFF_DINV  10686464u    // 50048 f32             200192
#define OFF_XBF   10886656u    // NN*128 bf16           12800000
#define OFF_XB2   23686656u    // NN*128 bf16           12800000
#define OFF_XB3   36486656u    // NN*128 bf16           12800000
#define OFF_H8    49286656u    // NN*128 fp8            6400000
#define OFF_H8C   55686656u    // 50048*384 fp8         19218432
#define OFF_HH    74905088u    // 50048 f32             200192
#define OFF_WT    75105280u    // 3*128*128 bf16        98304
#define OFF_SB8   75203584u    // 256*384 fp8           98304
#define OFF_SS    75301888u    // 256 f32               1024   -> total 75302912

__device__ __forceinline__ float b2f(ushort h){
  union { unsigned u; float f; } c; c.u = ((unsigned)h) << 16; return c.f;
}
__device__ __forceinline__ ushort f2b(float f){
  union { float f; unsigned u; } c; c.f = f;
  unsigned u = c.u;
  return (ushort)((u + 0x7fffu + ((u >> 16) & 1u)) >> 16);
}

// async global -> LDS, 16B per lane; lds dest = base + lane*16 (wave-uniform base)
__device__ __forceinline__ void gl16(const void* g, void* l){
  __builtin_amdgcn_global_load_lds((const __attribute__((address_space(1))) void*)g,
                                   (__attribute__((address_space(3))) void*)l, 16, 0, 0);
}

__global__ void k_convert(const float* __restrict__ s, ushort* __restrict__ d, int n4){
  int i = blockIdx.x * blockDim.x + threadIdx.x;
  if (i >= n4) return;
  float4 v = reinterpret_cast<const float4*>(s)[i];
  ushort4 o; o.x = f2b(v.x); o.y = f2b(v.y); o.z = f2b(v.z); o.w = f2b(v.w);
  reinterpret_cast<ushort4*>(d)[i] = o;
}

// f32 -> fp8 e4m3, 4 at a time
__global__ void k_conv8(const float* __restrict__ s, unsigned* __restrict__ d, int n4){
  int i = blockIdx.x * blockDim.x + threadIdx.x;
  if (i >= n4) return;
  float4 v = reinterpret_cast<const float4*>(s)[i];
  int p = __builtin_amdgcn_cvt_pk_fp8_f32(v.x, v.y, 0, false);
  p = __builtin_amdgcn_cvt_pk_fp8_f32(v.z, v.w, p, true);
  d[i] = (unsigned)p;
}

// Wt[n][k] = bf16(W[k][n])
__global__ void k_twc(const float* __restrict__ W, ushort* __restrict__ Wt){
  int n = blockIdx.x, k = threadIdx.x;
  Wt[n * FD + k] = f2b(W[k * FD + n]);
}

// phase A: bin edges by dst>>9, dense bucket appends
__global__ __launch_bounds__(256) void k_bin(const int* __restrict__ ei,
                                             int* __restrict__ bucketPos,
                                             unsigned* __restrict__ be){
  __shared__ int hist[NB], base[NB], off[NB];
  int t = threadIdx.x;
  for (int i = t; i < NB; i += 256) hist[i] = 0;
  __syncthreads();
  int e0 = blockIdx.x * EPB;
  int e1 = min(e0 + EPB, NE);
  for (int e = e0 + t; e < e1; e += 256)
    atomicAdd(&hist[ei[NE + e] >> 9], 1);
  __syncthreads();
  for (int i = t; i < NB; i += 256){
    base[i] = atomicAdd(&bucketPos[i], hist[i]);
    off[i] = 0;
  }
  __syncthreads();
  for (int e = e0 + t; e < e1; e += 256){
    int d = ei[NE + e], s = ei[e];
    int b = d >> 9;
    int p = base[b] + atomicAdd(&off[b], 1);
    if (p < BCAP) be[(size_t)b * BCAP + p] = ((unsigned)(d & 511) << 16) | (unsigned)s;
  }
}

// phase B: one block per bucket; LDS degree counters; L2-local col scatter
__global__ __launch_bounds__(256) void k_build(const int* __restrict__ bucketPos,
                                               const unsigned* __restrict__ be,
                                               int* __restrict__ cnt,
                                               ushort* __restrict__ col){
  __shared__ int lcnt[512];
  int t = threadIdx.x, b = blockIdx.x;
  for (int i = t; i < 512; i += 256) lcnt[i] = 0;
  __syncthreads();
  int nE = min(bucketPos[b], BCAP);
  const unsigned* bb = be + (size_t)b * BCAP;
  for (int i = t; i < nE; i += 256){
    unsigned u = bb[i];
    int dl = u >> 16, s = u & 0xffffu;
    int pos = atomicAdd(&lcnt[dl], 1);
    if (pos < MAXDEG) col[(size_t)(b * 512 + dl) * MAXDEG + pos] = (ushort)s;
  }
  __syncthreads();
  for (int i = t; i < 512; i += 256){
    int n = b * 512 + i;
    if (n < NN) cnt[n] = lcnt[i];
  }
}

__global__ void k_dinv(const int* __restrict__ cnt, float* __restrict__ dinv){
  int i = blockIdx.x * blockDim.x + threadIdx.x;
  if (i < NN) dinv[i] = rsqrtf((float)(cnt[i] + 1));
}

// Layer GEMM: C8[M][128] = fp8( rs[r] * (A[M][K] @ B[128][K]^T) )
// BM=64, BN=128, BK=64; 4 waves (2x2). A via global_load_lds; B from global.
__global__ __launch_bounds__(256) void k_gemm(
    const ushort* __restrict__ A, int lda,
    const ushort* __restrict__ B,              // [128][K], ldb = K
    unsigned char* __restrict__ C8, int M, int K,
    const float* __restrict__ rs){
  __shared__ __align__(16) ushort Al[64 * 64];   // 8 KB
  const int t = threadIdx.x;
  const int lane = t & 63, w = t >> 6;
  const int wr = w >> 1, wc = w & 1;
  const int ln = lane & 15, hi = lane >> 4;
  const int mBase = blockIdx.x * 64;

  f32x4 zero = {0.f, 0.f, 0.f, 0.f};
  f32x4 acc[2][4];
  #pragma unroll
  for (int i = 0; i < 2; ++i)
    #pragma unroll
    for (int j = 0; j < 4; ++j) acc[i][j] = zero;

  for (int kb = 0; kb < K; kb += 64){
    __syncthreads();
    #pragma unroll
    for (int cc = 0; cc < 2; ++cc){            // A: 8 chunks of 1KB, 2/wave
      int c = w * 2 + cc;
      int o = c * 1024 + lane * 16;            // linear LDS byte offset
      int row = o >> 7;
      int seg = ((o & 127) ^ ((row & 7) << 4)) >> 4;   // inverse swizzle on source
      gl16(A + (size_t)(mBase + row) * lda + kb + seg * 8,
           (char*)Al + c * 1024);
    }
    short8 b[4][2];
    #pragma unroll
    for (int fn = 0; fn < 4; ++fn)
      #pragma unroll
      for (int ks = 0; ks < 2; ++ks)
        b[fn][ks] = *reinterpret_cast<const short8*>(
            B + (size_t)(wc * 64 + fn * 16 + ln) * K + kb + ks * 32 + hi * 8);
    __syncthreads();
    #pragma unroll
    for (int ks = 0; ks < 2; ++ks){
      short8 a[2];
      #pragma unroll
      for (int f = 0; f < 2; ++f){
        int ra = wr * 32 + f * 16 + ln;
        int oa = (ra * 128 + ks * 64 + hi * 16) ^ ((ra & 7) << 4);
        a[f] = *reinterpret_cast<const short8*>((const char*)Al + oa);
      }
      #pragma unroll
      for (int fm = 0; fm < 2; ++fm)
        #pragma unroll
        for (int fn = 0; fn < 4; ++fn)
          acc[fm][fn] = __builtin_amdgcn_mfma_f32_16x16x32_bf16(a[fm], b[fn][ks], acc[fm][fn], 0, 0, 0);
    }
  }
  #pragma unroll
  for (int fm = 0; fm < 2; ++fm){
    int r0 = mBase + wr * 32 + fm * 16 + hi * 4;
    float rsv[4] = {0.f, 0.f, 0.f, 0.f};
    #pragma unroll
    for (int j = 0; j < 4; ++j) if (r0 + j < M) rsv[j] = rs[r0 + j];
    #pragma unroll
    for (int fn = 0; fn < 4; ++fn){
      int cg = wc * 64 + fn * 16 + ln;
      f32x4 v = acc[fm][fn];
      int p01 = __builtin_amdgcn_cvt_pk_fp8_f32(v[0] * rsv[0], v[1] * rsv[1], 0, false);
      int p23 = __builtin_amdgcn_cvt_pk_fp8_f32(v[2] * rsv[2], v[3] * rsv[3], 0, false);
      if (r0     < M) C8[(size_t)(r0    ) * FD + cg] = (unsigned char)(p01);
      if (r0 + 1 < M) C8[(size_t)(r0 + 1) * FD + cg] = (unsigned char)(p01 >> 8);
      if (r0 + 2 < M) C8[(size_t)(r0 + 2) * FD + cg] = (unsigned char)(p23);
      if (r0 + 3 < M) C8[(size_t)(r0 + 3) * FD + cg] = (unsigned char)(p23 >> 8);
    }
  }
}

// Persistent fused SOM: fp8 GEMM (B=lattice fully LDS-resident) + argmin + gaussian.
// grid=256 blocks x 256 threads (4 waves, 2x2); grid-strides 32-row tiles.
__global__ __launch_bounds__(256) void k_gsom(
    const unsigned char* __restrict__ A8,   // H8cat [50048][384] fp8
    const unsigned char* __restrict__ B8,   // Sb8 [256][384] fp8
    const float* __restrict__ ss, const float* __restrict__ hh,
    const int* __restrict__ batch, float* __restrict__ G){
  __shared__ __align__(16) unsigned char Bl[256 * 384];    // 96 KB
  __shared__ __align__(16) unsigned char Aq[2][TM * 384];  // 2 x 12 KB
  __shared__ float l_ss[NU];
  __shared__ float redv[2][TM];
  __shared__ int   redi[2][TM];
  __shared__ float l_hs[TM];
  __shared__ int   l_win[TM];
  __shared__ int   l_bat[TM];

  const int t = threadIdx.x;
  const int lane = t & 63, w = t >> 6;
  const int wr = w >> 1, wc = w & 1;          // 2x2 wave grid
  const int ln = lane & 15, hi = lane >> 4;

  l_ss[t] = ss[t];
  // stage full B (96 chunks of 1KB, 24 per wave), inverse-swizzled source
  #pragma unroll 4
  for (int i = 0; i < 24; ++i){
    int c = w * 24 + i;
    unsigned o = (unsigned)c * 1024u + (unsigned)lane * 16u;
    unsigned row = o / 384u;
    gl16(B8 + (o ^ ((row & 7u) << 4)), Bl + c * 1024);
  }
  int ti = blockIdx.x;
  {
    const unsigned char* src = A8 + (size_t)ti * (TM * 384);
    #pragma unroll
    for (int i = 0; i < 3; ++i){
      int c = w * 3 + i;
      unsigned o = (unsigned)c * 1024u + (unsigned)lane * 16u;
      unsigned row = o / 384u;
      gl16(src + (o ^ ((row & 7u) << 4)), Aq[0] + c * 1024);
    }
  }
  __syncthreads();

  const int arow = wr * 16 + ln;              // wave-local A row 0..31
  const unsigned aswz = (unsigned)((arow & 7) << 4);
  int cur = 0;
  for (; ti < NT; ti += 256){
    int nxt = ti + 256;
    if (nxt < NT){                            // prefetch next tile into other buffer
      const unsigned char* src = A8 + (size_t)nxt * (TM * 384);
      #pragma unroll
      for (int i = 0; i < 3; ++i){
        int c = w * 3 + i;
        unsigned o = (unsigned)c * 1024u + (unsigned)lane * 16u;
        unsigned row = o / 384u;
        gl16(src + (o ^ ((row & 7u) << 4)), Aq[cur ^ 1] + c * 1024);
      }
    }
    // ---- fp8 K-loop: 6 kp steps x (2 MFMA halves x 8 fn) ----
    f32x4 acc[8];
    #pragma unroll
    for (int i = 0; i < 8; ++i) acc[i] = (f32x4){0.f, 0.f, 0.f, 0.f};
    const unsigned char* Ab = Aq[cur];
    #pragma unroll
    for (int kp = 0; kp < 6; ++kp){
      unsigned ko = (unsigned)(kp * 64 + hi * 16);
      long2v av = *reinterpret_cast<const long2v*>(Ab + arow * 384 + (ko ^ aswz));
      #pragma unroll
      for (int fn = 0; fn < 8; ++fn){
        int c = wc * 128 + fn * 16 + ln;
        long2v bv = *reinterpret_cast<const long2v*>(Bl + c * 384 + (ko ^ ((unsigned)((c & 7) << 4))));
        acc[fn] = __builtin_amdgcn_mfma_f32_16x16x32_fp8_fp8(av.x, bv.x, acc[fn], 0, 0, 0);
        acc[fn] = __builtin_amdgcn_mfma_f32_16x16x32_fp8_fp8(av.y, bv.y, acc[fn], 0, 0, 0);
      }
    }
    // ---- per-wave argmin: lane's rows are hi*4+j; cols wc*128+fn*16+ln ----
    #pragma unroll
    for (int j = 0; j < 4; ++j){
      float mv = 3.4e38f; int mi = 0;
      #pragma unroll
      for (int fn = 0; fn < 8; ++fn){
        int c = wc * 128 + fn * 16 + ln;
        float v = l_ss[c] - 2.f * acc[fn][j];
        if (v < mv || (v == mv && c < mi)){ mv = v; mi = c; }
      }
      #pragma unroll
      for (int m = 1; m < 16; m <<= 1){
        float ov = __shfl_xor(mv, m);
        int   oi = __shfl_xor(mi, m);
        if (ov < mv || (ov == mv && oi < mi)){ mv = ov; mi = oi; }
      }
      if (ln == 0){
        int row = wr * 16 + hi * 4 + j;
        redv[wc][row] = mv; redi[wc][row] = mi;
      }
    }
    __syncthreads();
    if (t < TM){
      int r = ti * TM + t;
      float mv = redv[0][t]; int mi = redi[0][t];
      float ov = redv[1][t]; int oi = redi[1][t];
      if (ov < mv || (ov == mv && oi < mi)){ mv = ov; mi = oi; }
      if (r < NN){
        float d2 = fmaxf(hh[r] + mv, 0.f);
        l_hs[t] = __expf(-sqrtf(d2));
        l_win[t] = mi;
        l_bat[t] = batch[r];
      } else {
        l_hs[t] = 0.f; l_win[t] = 0; l_bat[t] = -1;
      }
    }
    __syncthreads();
    // ---- gaussian: wave w handles rows [w*8, w*8+8); lane owns 4 cells ----
    {
      float g0 = 0.f, g1 = 0.f, g2 = 0.f, g3 = 0.f;
      int curb = -1;
      int c0 = lane * 4;
      float cx = (float)(c0 >> 4);
      #pragma unroll
      for (int rr = 0; rr < 8; ++rr){
        int row = w * 8 + rr;
        int b = l_bat[row];
        if (b < 0) continue;
        if (b != curb){
          if (curb >= 0){
            atomicAdd(&G[curb * NU + c0    ], g0);
            atomicAdd(&G[curb * NU + c0 + 1], g1);
            atomicAdd(&G[curb * NU + c0 + 2], g2);
            atomicAdd(&G[curb * NU + c0 + 3], g3);
            g0 = g1 = g2 = g3 = 0.f;
          }
          curb = b;
        }
        float hs = l_hs[row];
        int win = l_win[row];
        float wi = (float)(win >> 4), wj = (float)(win & 15);
        float dx = cx - wi;
        float ex = hs * __expf(-dx * dx * 0.125f);
        float dy0 = (float)((c0    ) & 15) - wj;
        float dy1 = (float)((c0 + 1) & 15) - wj;
        float dy2 = (float)((c0 + 2) & 15) - wj;
        float dy3 = (float)((c0 + 3) & 15) - wj;
        g0 += ex * __expf(-dy0 * dy0 * 0.125f);
        g1 += ex * __expf(-dy1 * dy1 * 0.125f);
        g2 += ex * __expf(-dy2 * dy2 * 0.125f);
        g3 += ex * __expf(-dy3 * dy3 * 0.125f);
      }
      if (curb >= 0){
        atomicAdd(&G[curb * NU + c0    ], g0);
        atomicAdd(&G[curb * NU + c0 + 1], g1);
        atomicAdd(&G[curb * NU + c0 + 2], g2);
        atomicAdd(&G[curb * NU + c0 + 3], g3);
      }
    }
    __syncthreads();
    cur ^= 1;
  }
}

// wave per node, 4 groups x 16 lanes; lane owns 8 features (8B fp8 rows).
// outputs: xn (bf16 dense, next-layer GEMM A), h8c slice (fp8 concat), hh.
__global__ __launch_bounds__(256) void k_agg(
    const unsigned char* __restrict__ hs8, const float* __restrict__ dinv,
    const int* __restrict__ cnt, const ushort* __restrict__ col,
    const float* __restrict__ bias, ushort* __restrict__ xn,
    unsigned char* __restrict__ h8c, int cOff,
    float* __restrict__ hh){
  int lane = threadIdx.x & 63;
  int n = blockIdx.x * 4 + (threadIdx.x >> 6);
  if (n >= NN) return;
  const int g = lane >> 4, ln = lane & 15;
  const int f0 = ln * 8;
  float acc[8] = {0.f,0.f,0.f,0.f,0.f,0.f,0.f,0.f};
  if (g == 0){                     // self loop
    uint2 sv = *reinterpret_cast<const uint2*>(hs8 + (size_t)n * FD + f0);
    f32x2 e;
    e = __builtin_amdgcn_cvt_pk_f32_fp8((int)sv.x, false); acc[0] = e.x; acc[1] = e.y;
    e = __builtin_amdgcn_cvt_pk_f32_fp8((int)sv.x, true ); acc[2] = e.x; acc[3] = e.y;
    e = __builtin_amdgcn_cvt_pk_f32_fp8((int)sv.y, false); acc[4] = e.x; acc[5] = e.y;
    e = __builtin_amdgcn_cvt_pk_f32_fp8((int)sv.y, true ); acc[6] = e.x; acc[7] = e.y;
  }
  int ne = cnt[n]; if (ne > MAXDEG) ne = MAXDEG;
  const ushort* cl = col + (size_t)n * MAXDEG;
  for (int j = 0; j < ne; j += 16){
    int i0 = j + g, i1 = j + 4 + g, i2 = j + 8 + g, i3 = j + 12 + g;
    int s0 = n, s1 = n, s2 = n, s3 = n;
    float w0 = 0.f, w1 = 0.f, w2 = 0.f, w3 = 0.f;
    if (i0 < ne){ s0 = cl[i0]; w0 = 1.f; }
    if (i1 < ne){ s1 = cl[i1]; w1 = 1.f; }
    if (i2 < ne){ s2 = cl[i2]; w2 = 1.f; }
    if (i3 < ne){ s3 = cl[i3]; w3 = 1.f; }
    uint2 r0v = *reinterpret_cast<const uint2*>(hs8 + (size_t)s0 * FD + f0);
    uint2 r1v = *reinterpret_cast<const uint2*>(hs8 + (size_t)s1 * FD + f0);
    uint2 r2v = *reinterpret_cast<const uint2*>(hs8 + (size_t)s2 * FD + f0);
    uint2 r3v = *reinterpret_cast<const uint2*>(hs8 + (size_t)s3 * FD + f0);
    f32x2 e;
    e = __builtin_amdgcn_cvt_pk_f32_fp8((int)r0v.x, false); acc[0] += e.x*w0; acc[1] += e.y*w0;
    e = __builtin_amdgcn_cvt_pk_f32_fp8((int)r0v.x, true ); acc[2] += e.x*w0; acc[3] += e.y*w0;
    e = __builtin_amdgcn_cvt_pk_f32_fp8((int)r0v.y, false); acc[4] += e.x*w0; acc[5] += e.y*w0;
    e = __builtin_amdgcn_cvt_pk_f32_fp8((int)r0v.y, true ); acc[6] += e.x*w0; acc[7] += e.y*w0;
    e = __builtin_amdgcn_cvt_pk_f32_fp8((int)r1v.x, false); acc[0] += e.x*w1; acc[1] += e.y*w1;
    e = __builtin_amdgcn_cvt_pk_f32_fp8((int)r1v.x, true ); acc[2] += e.x*w1; acc[3] += e.y*w1;
    e = __builtin_amdgcn_cvt_pk_f32_fp8((int)r1v.y, false); acc[4] += e.x*w1; acc[5] += e.y*w1;
    e = __builtin_amdgcn_cvt_pk_f32_fp8((int)r1v.y, true ); acc[6] += e.x*w1; acc[7] += e.y*w1;
    e = __builtin_amdgcn_cvt_pk_f32_fp8((int)r2v.x, false); acc[0] += e.x*w2; acc[1] += e.y*w2;
    e = __builtin_amdgcn_cvt_pk_f32_fp8((int)r2v.x, true ); acc[2] += e.x*w2; acc[3] += e.y*w2;
    e = __builtin_amdgcn_cvt_pk_f32_fp8((int)r2v.y, false); acc[4] += e.x*w2; acc[5] += e.y*w2;
    e = __builtin_amdgcn_cvt_pk_f32_fp8((int)r2v.y, true ); acc[6] += e.x*w2; acc[7] += e.y*w2;
    e = __builtin_amdgcn_cvt_pk_f32_fp8((int)r3v.x, false); acc[0] += e.x*w3; acc[1] += e.y*w3;
    e = __builtin_amdgcn_cvt_pk_f32_fp8((int)r3v.x, true ); acc[2] += e.x*w3; acc[3] += e.y*w3;
    e = __builtin_amdgcn_cvt_pk_f32_fp8((int)r3v.y, false); acc[4] += e.x*w3; acc[5] += e.y*w3;
    e = __builtin_amdgcn_cvt_pk_f32_fp8((int)r3v.y, true ); acc[6] += e.x*w3; acc[7] += e.y*w3;
  }
  #pragma unroll
  for (int k = 0; k < 8; ++k){
    acc[k] += __shfl_xor(acc[k], 16);
    acc[k] += __shfl_xor(acc[k], 32);
  }
  float di = dinv[n];
  float ssq = 0.f;
  float vv[8];
  short8 o;
  #pragma unroll
  for (int k = 0; k < 8; ++k){
    float v = acc[k] * di + bias[f0 + k];
    v = v > 0.f ? v : 0.01f * v;
    ssq += v * v;
    vv[k] = v;
    o[k] = (short)f2b(v);
  }
  if (g == 0){
    *reinterpret_cast<short8*>(xn + (size_t)n * FD + f0) = o;
    int pa = __builtin_amdgcn_cvt_pk_fp8_f32(vv[0], vv[1], 0, false);
    pa = __builtin_amdgcn_cvt_pk_fp8_f32(vv[2], vv[3], pa, true);
    int pb = __builtin_amdgcn_cvt_pk_fp8_f32(vv[4], vv[5], 0, false);
    pb = __builtin_amdgcn_cvt_pk_fp8_f32(vv[6], vv[7], pb, true);
    uint2 pk; pk.x = (unsigned)pa; pk.y = (unsigned)pb;
    *reinterpret_cast<uint2*>(h8c + (size_t)n * KH + cOff + f0) = pk;
    #pragma unroll
    for (int m = 1; m < 16; m <<= 1) ssq += __shfl_xor(ssq, m);
    if (ln == 0){
      if (cOff == 0) hh[n] = ssq;
      else           hh[n] += ssq;
    }
  }
}

__global__ void k_ss(const float* __restrict__ S, float* __restrict__ ss){
  int u = blockIdx.x, lane = threadIdx.x;
  const float* p = S + (size_t)u * KH + lane * 6;
  float s = 0.f;
  #pragma unroll
  for (int j = 0; j < 6; ++j){ float v = p[j]; s += v * v; }
  #pragma unroll
  for (int o = 32; o; o >>= 1) s += __shfl_down(s, o);
  if (lane == 0) ss[u] = s;
}

__global__ void k_out(const float* __restrict__ G, const float* __restrict__ lw,
                      const float* __restrict__ lb, float* __restrict__ out){
  int b = blockIdx.x, lane = threadIdx.x;
  float s = 0.f;
  #pragma unroll
  for (int j = 0; j < 4; ++j) s += G[b * NU + lane * 4 + j] * lw[lane * 4 + j];
  #pragma unroll
  for (int o = 32; o; o >>= 1) s += __shfl_down(s, o);
  if (lane == 0) out[b] = 1.f / (1.f + __expf(-(s + lb[0])));
}

extern "C" void kernel_launch(void* const* d_in, const int* in_sizes, int n_in,
                              void* d_out, int out_size, void* d_ws, size_t ws_size,
                              hipStream_t stream){
  const float* x   = (const float*)d_in[0];
  const int*   ei  = (const int*)d_in[1];
  const int*   bat = (const int*)d_in[2];
  const float* W1  = (const float*)d_in[3];
  const float* b1  = (const float*)d_in[4];
  const float* W2  = (const float*)d_in[5];
  const float* b2  = (const float*)d_in[6];
  const float* W3  = (const float*)d_in[7];
  const float* b3  = (const float*)d_in[8];
  const float* S   = (const float*)d_in[9];
  const float* lw  = (const float*)d_in[10];
  const float* lb  = (const float*)d_in[11];
  float* out = (float*)d_out;
  char* w = (char*)d_ws;

  int*      pos  = (int*)     (w + OFF_POS);
  float*    G    = (float*)   (w + OFF_G);
  int*      cnt  = (int*)     (w + OFF_CNT);
  unsigned* be   = (unsigned*)(w + OFF_BE);
  ushort*   col  = (ushort*)  (w + OFF_COL);
  float*    dinv = (float*)   (w + OFF_DINV);
  ushort*   xbf  = (ushort*)  (w + OFF_XBF);
  ushort*   xb2  = (ushort*)  (w + OFF_XB2);
  ushort*   xb3  = (ushort*)  (w + OFF_XB3);
  unsigned char* h8  = (unsigned char*)(w + OFF_H8);
  unsigned char* h8c = (unsigned char*)(w + OFF_H8C);
  float*    hh   = (float*)   (w + OFF_HH);
  ushort*   Wt   = (ushort*)  (w + OFF_WT);
  unsigned char* sb8 = (unsigned char*)(w + OFF_SB8);
  float*    ss   = (float*)   (w + OFF_SS);

  hipMemsetAsync(w, 0, 66048, stream);                      // pos + G

  k_convert<<<6250, 256, 0, stream>>>(x, xbf, 1600000);
  k_conv8<<<96, 256, 0, stream>>>(S, (unsigned*)sb8, 24576);
  k_twc<<<128, 128, 0, stream>>>(W1, Wt);
  k_twc<<<128, 128, 0, stream>>>(W2, Wt + 16384);
  k_twc<<<128, 128, 0, stream>>>(W3, Wt + 32768);

  k_bin<<<196, 256, 0, stream>>>(ei, pos, be);
  k_build<<<NB, 256, 0, stream>>>(pos, be, cnt, col);
  k_dinv<<<196, 256, 0, stream>>>(cnt, dinv);

  dim3 blk(256);
  // layer 1
  k_gemm<<<782, blk, 0, stream>>>(xbf, FD, Wt, h8, NN, FD, dinv);
  k_agg<<<12500, 256, 0, stream>>>(h8, dinv, cnt, col, b1, xb2, h8c, 0, hh);
  // layer 2
  k_gemm<<<782, blk, 0, stream>>>(xb2, FD, Wt + 16384, h8, NN, FD, dinv);
  k_agg<<<12500, 256, 0, stream>>>(h8, dinv, cnt, col, b2, xb3, h8c, 128, hh);
  // layer 3 (xn output written to xb2 slot, unused afterwards)
  k_gemm<<<782, blk, 0, stream>>>(xb3, FD, Wt + 32768, h8, NN, FD, dinv);
  k_agg<<<12500, 256, 0, stream>>>(h8, dinv, cnt, col, b3, xb2, h8c, 256, hh);

  k_ss<<<256, 64, 0, stream>>>(S, ss);
  // persistent fused SOM
  k_gsom<<<256, blk, 0, stream>>>(h8c, sb8, ss, hh, bat, G);
  k_out<<<64, 64, 0, stream>>>(G, lw, lb, out);
}

// Round 8
// 232.752 us; speedup vs baseline: 1.1409x; 1.1409x over previous
//
#include <hip/hip_runtime.h>

#define NN 50000
#define NE 800000
#define FD 128
#define KH 384
#define NU 256
#define NG 64
#define MAXDEG 64
#define NB 98          // dst buckets of 512 nodes
#define BCAP 10240     // per-bucket capacity
#define EPB 4096       // edges per k_bin block
#define LDA 136        // padded bf16 row (272 B) for GEMM A operands
#define LDH 400        // padded fp8 row (400 B) for H-concat

typedef __attribute__((__ext_vector_type__(8))) short short8;
typedef __attribute__((__ext_vector_type__(4))) float f32x4;
typedef __attribute__((__ext_vector_type__(2))) float f32x2;

// ---- ws layout (bytes, 16B-aligned) ----
#define OFF_POS   0u           // NB int (+pad)         512     [memset]
#define OFF_G     512u         // 64*256 f32            65536   [memset]
#define OFF_CNT   66048u       // 50048 int             200192
#define OFF_BE    266240u      // NB*BCAP u32           4014080
#define OFF_COL   4280320u     // 50048*64 u16          6406144
#define OFF_DINV  10686464u    // 50048 f32             200192
#define OFF_XBF   10886656u    // 50048*272B bf16pad    13613056
#define OFF_XB2   24499712u    // 50048*272B            13613056
#define OFF_XB3   38112768u    // 50048*272B            13613056
#define OFF_H8    51725824u    // 50048*128 fp8         6406144
#define OFF_H8C   58131968u    // 50048*400B fp8pad     20019200
#define OFF_HH    78151168u    // 50048 f32             200192
#define OFF_WR    78351360u    // 3*16384 ushort        98304
#define OFF_SBR   78449664u    // 12*256*32 fp8         98304
#define OFF_SS    78547968u    // 256 f32               1024   -> total 78548992

__device__ __forceinline__ float b2f(ushort h){
  union { unsigned u; float f; } c; c.u = ((unsigned)h) << 16; return c.f;
}
__device__ __forceinline__ ushort f2b(float f){
  union { float f; unsigned u; } c; c.f = f;
  unsigned u = c.u;
  return (ushort)((u + 0x7fffu + ((u >> 16) & 1u)) >> 16);
}

// async global -> LDS: lds dest wave-uniform base; HW adds lane*16
__device__ __forceinline__ void gl16(const void* g, void* l){
  __builtin_amdgcn_global_load_lds((const __attribute__((address_space(1))) void*)g,
                                   (__attribute__((address_space(3))) void*)l, 16, 0, 0);
}

// x f32 [50000][128] -> padded bf16 rows of 136 ushorts
__global__ void k_convert(const float* __restrict__ s, ushort4* __restrict__ d, int n4){
  int i = blockIdx.x * blockDim.x + threadIdx.x;
  if (i >= n4) return;
  int r = i >> 5, q = i & 31;
  float4 v = reinterpret_cast<const float4*>(s)[i];
  ushort4 o; o.x = f2b(v.x); o.y = f2b(v.y); o.z = f2b(v.z); o.w = f2b(v.w);
  d[r * 34 + q] = o;
}

// S f32 [256][384] -> fp8 frag-contiguous: byte idx = kp*8192 + c*32 + k8*8 + b
__global__ void k_s8r(const float* __restrict__ S, unsigned* __restrict__ d){
  int tid = blockIdx.x * blockDim.x + threadIdx.x;   // 24576 = 256 * 96
  int c = tid / 96, kq = tid % 96;
  int k0 = kq * 4;
  float4 v = *reinterpret_cast<const float4*>(S + (size_t)c * KH + k0);
  int p = __builtin_amdgcn_cvt_pk_fp8_f32(v.x, v.y, 0, false);
  p = __builtin_amdgcn_cvt_pk_fp8_f32(v.z, v.w, p, true);
  int kp = k0 >> 5, k8 = (k0 >> 3) & 3;
  d[(kp * 8192 + c * 32 + k8 * 8 + (k0 & 7)) >> 2] = (unsigned)p;
}

// W f32 [128][128] (k,n) -> bf16 frag-contiguous: ushort idx = kp*4096 + n*32 + k8*8 + b
__global__ void k_twr(const float* __restrict__ W, ushort* __restrict__ Wr){
  int n = blockIdx.x, k = threadIdx.x;
  Wr[(k >> 5) * 4096 + n * 32 + ((k >> 3) & 3) * 8 + (k & 7)] = f2b(W[k * FD + n]);
}

// phase A: bin edges by dst>>9, dense bucket appends
__global__ __launch_bounds__(256) void k_bin(const int* __restrict__ ei,
                                             int* __restrict__ bucketPos,
                                             unsigned* __restrict__ be){
  __shared__ int hist[NB], base[NB], off[NB];
  int t = threadIdx.x;
  for (int i = t; i < NB; i += 256) hist[i] = 0;
  __syncthreads();
  int e0 = blockIdx.x * EPB;
  int e1 = min(e0 + EPB, NE);
  for (int e = e0 + t; e < e1; e += 256)
    atomicAdd(&hist[ei[NE + e] >> 9], 1);
  __syncthreads();
  for (int i = t; i < NB; i += 256){
    base[i] = atomicAdd(&bucketPos[i], hist[i]);
    off[i] = 0;
  }
  __syncthreads();
  for (int e = e0 + t; e < e1; e += 256){
    int d = ei[NE + e], s = ei[e];
    int b = d >> 9;
    int p = base[b] + atomicAdd(&off[b], 1);
    if (p < BCAP) be[(size_t)b * BCAP + p] = ((unsigned)(d & 511) << 16) | (unsigned)s;
  }
}

// phase B: one block per bucket; LDS degree counters; L2-local col scatter
__global__ __launch_bounds__(256) void k_build(const int* __restrict__ bucketPos,
                                               const unsigned* __restrict__ be,
                                               int* __restrict__ cnt,
                                               ushort* __restrict__ col){
  __shared__ int lcnt[512];
  int t = threadIdx.x, b = blockIdx.x;
  for (int i = t; i < 512; i += 256) lcnt[i] = 0;
  __syncthreads();
  int nE = min(bucketPos[b], BCAP);
  const unsigned* bb = be + (size_t)b * BCAP;
  for (int i = t; i < nE; i += 256){
    unsigned u = bb[i];
    int dl = u >> 16, s = u & 0xffffu;
    int pos = atomicAdd(&lcnt[dl], 1);
    if (pos < MAXDEG) col[(size_t)(b * 512 + dl) * MAXDEG + pos] = (ushort)s;
  }
  __syncthreads();
  for (int i = t; i < 512; i += 256){
    int n = b * 512 + i;
    if (n < NN) cnt[n] = lcnt[i];
  }
}

__global__ void k_dinv(const int* __restrict__ cnt, float* __restrict__ dinv){
  int i = blockIdx.x * blockDim.x + threadIdx.x;
  if (i < NN) dinv[i] = rsqrtf((float)(cnt[i] + 1));
}

// Layer GEMM: C8[M][128] = fp8( rs[r] * (A[M][128] @ W^T) )
// tile 64r x 128c, K=128 whole-tile in LDS; one barrier per block.
__global__ __launch_bounds__(256) void k_gemm(
    const ushort* __restrict__ A,              // padded rows of LDA ushorts
    const ushort* __restrict__ Wr,             // frag-contiguous [4][128][32]
    unsigned char* __restrict__ C8, int M,
    const float* __restrict__ rs){
  __shared__ __align__(16) ushort Al[64 * LDA];   // 17408 B
  const int t = threadIdx.x;
  const int lane = t & 63, w = t >> 6;
  const int wM = w >> 1, wN = w & 1;
  const int ln = lane & 15, hi = lane >> 4;
  const int mBase = blockIdx.x * 64;

  const char* Asrc = (const char*)(A + (size_t)mBase * LDA);
  #pragma unroll
  for (int j = 0; j < 4; ++j){
    int base = w * 1024 + j * 4096;
    gl16(Asrc + base + lane * 16, (char*)Al + base);
  }
  if (w == 0) gl16(Asrc + 16384 + lane * 16, (char*)Al + 16384);
  __syncthreads();

  f32x4 acc[2][4];
  #pragma unroll
  for (int i = 0; i < 2; ++i)
    #pragma unroll
    for (int j = 0; j < 4; ++j) acc[i][j] = (f32x4){0.f, 0.f, 0.f, 0.f};

  #pragma unroll
  for (int kp = 0; kp < 4; ++kp){
    short8 a[2], b[4];
    #pragma unroll
    for (int fm = 0; fm < 2; ++fm)
      a[fm] = *reinterpret_cast<const short8*>(
          (const char*)Al + (wM * 32 + fm * 16 + ln) * 272 + kp * 64 + hi * 16);
    #pragma unroll
    for (int fn = 0; fn < 4; ++fn)
      b[fn] = *reinterpret_cast<const short8*>(
          Wr + kp * 4096 + (wN * 64 + fn * 16 + ln) * 32 + hi * 8);
    #pragma unroll
    for (int fm = 0; fm < 2; ++fm)
      #pragma unroll
      for (int fn = 0; fn < 4; ++fn)
        acc[fm][fn] = __builtin_amdgcn_mfma_f32_16x16x32_bf16(a[fm], b[fn], acc[fm][fn], 0, 0, 0);
  }
  #pragma unroll
  for (int fm = 0; fm < 2; ++fm){
    int r0 = mBase + wM * 32 + fm * 16 + hi * 4;
    float rsv[4] = {0.f, 0.f, 0.f, 0.f};
    #pragma unroll
    for (int j = 0; j < 4; ++j) if (r0 + j < M) rsv[j] = rs[r0 + j];
    #pragma unroll
    for (int fn = 0; fn < 4; ++fn){
      int cg = wN * 64 + fn * 16 + ln;
      f32x4 v = acc[fm][fn];
      int p01 = __builtin_amdgcn_cvt_pk_fp8_f32(v[0] * rsv[0], v[1] * rsv[1], 0, false);
      int p23 = __builtin_amdgcn_cvt_pk_fp8_f32(v[2] * rsv[2], v[3] * rsv[3], 0, false);
      if (r0     < M) C8[(size_t)(r0    ) * FD + cg] = (unsigned char)(p01);
      if (r0 + 1 < M) C8[(size_t)(r0 + 1) * FD + cg] = (unsigned char)(p01 >> 8);
      if (r0 + 2 < M) C8[(size_t)(r0 + 2) * FD + cg] = (unsigned char)(p23);
      if (r0 + 3 < M) C8[(size_t)(r0 + 3) * FD + cg] = (unsigned char)(p23 >> 8);
    }
  }
}

// Fused SOM: fp8 GEMM (whole 64x384 A-tile in LDS, B frag-contiguous from L2)
// + argmin + gaussian scatter. 782 blocks x 256 thr (4 waves, 2M x 2N).
__global__ __launch_bounds__(256) void k_gsom(
    const unsigned char* __restrict__ A8,   // h8c padded rows of LDH
    const unsigned char* __restrict__ Br,   // Sb8r [12][256][32]
    const float* __restrict__ ss, const float* __restrict__ hh,
    const int* __restrict__ batch, float* __restrict__ G, int M){
  __shared__ __align__(16) unsigned char Al[64 * LDH];  // 25600 B
  __shared__ float l_ss[NU];
  __shared__ float redv[2][64];
  __shared__ int   redi[2][64];
  __shared__ float l_hs[64];
  __shared__ int   l_win[64];
  __shared__ int   l_bat[64];

  const int t = threadIdx.x;
  const int lane = t & 63, w = t >> 6;
  const int wM = w >> 1, wN = w & 1;
  const int ln = lane & 15, hi = lane >> 4;
  const int mBase = blockIdx.x * 64;

  l_ss[t] = ss[t];
  const char* Asrc = (const char*)(A8 + (size_t)mBase * LDH);
  #pragma unroll
  for (int j = 0; j < 6; ++j){
    int base = w * 1024 + j * 4096;
    gl16(Asrc + base + lane * 16, (char*)Al + base);
  }
  if (w == 0) gl16(Asrc + 24576 + lane * 16, (char*)Al + 24576);
  __syncthreads();

  f32x4 acc[2][8];
  #pragma unroll
  for (int i = 0; i < 2; ++i)
    #pragma unroll
    for (int j = 0; j < 8; ++j) acc[i][j] = (f32x4){0.f, 0.f, 0.f, 0.f};

  #pragma unroll
  for (int kp = 0; kp < 12; ++kp){
    long av0 = *reinterpret_cast<const long*>(Al + (wM * 32 +      ln) * LDH + kp * 32 + hi * 8);
    long av1 = *reinterpret_cast<const long*>(Al + (wM * 32 + 16 + ln) * LDH + kp * 32 + hi * 8);
    #pragma unroll
    for (int fn = 0; fn < 8; ++fn){
      long bv = *reinterpret_cast<const long*>(Br + kp * 8192 + (wN * 128 + fn * 16 + ln) * 32 + hi * 8);
      acc[0][fn] = __builtin_amdgcn_mfma_f32_16x16x32_fp8_fp8(av0, bv, acc[0][fn], 0, 0, 0);
      acc[1][fn] = __builtin_amdgcn_mfma_f32_16x16x32_fp8_fp8(av1, bv, acc[1][fn], 0, 0, 0);
    }
  }

  // ---- per-wave argmin over its 128 cols, per row ----
  #pragma unroll
  for (int fm = 0; fm < 2; ++fm){
    #pragma unroll
    for (int j = 0; j < 4; ++j){
      float mv = 3.4e38f; int mi = 0;
      #pragma unroll
      for (int fn = 0; fn < 8; ++fn){
        int c = wN * 128 + fn * 16 + ln;
        float v = l_ss[c] - 2.f * acc[fm][fn][j];
        if (v < mv || (v == mv && c < mi)){ mv = v; mi = c; }
      }
      #pragma unroll
      for (int m = 1; m < 16; m <<= 1){
        float ov = __shfl_xor(mv, m);
        int   oi = __shfl_xor(mi, m);
        if (ov < mv || (ov == mv && oi < mi)){ mv = ov; mi = oi; }
      }
      if (ln == 0){
        int row = wM * 32 + fm * 16 + hi * 4 + j;
        redv[wN][row] = mv; redi[wN][row] = mi;
      }
    }
  }
  __syncthreads();
  if (t < 64){
    int r = mBase + t;
    float mv = redv[0][t]; int mi = redi[0][t];
    float ov = redv[1][t]; int oi = redi[1][t];
    if (ov < mv || (ov == mv && oi < mi)){ mv = ov; mi = oi; }
    if (r < M){
      float d2 = fmaxf(hh[r] + mv, 0.f);
      l_hs[t] = __expf(-sqrtf(d2));
      l_win[t] = mi;
      l_bat[t] = batch[r];
    } else {
      l_hs[t] = 0.f; l_win[t] = 0; l_bat[t] = -1;
    }
  }
  __syncthreads();
  // ---- gaussian: wave w handles rows [w*16, w*16+16); lane owns 4 cells ----
  {
    float g0 = 0.f, g1 = 0.f, g2 = 0.f, g3 = 0.f;
    int curb = -1;
    int c0 = lane * 4;
    float cx = (float)(c0 >> 4);
    #pragma unroll
    for (int rr = 0; rr < 16; ++rr){
      int row = w * 16 + rr;
      int b = l_bat[row];
      if (b < 0) continue;
      if (b != curb){
        if (curb >= 0){
          atomicAdd(&G[curb * NU + c0    ], g0);
          atomicAdd(&G[curb * NU + c0 + 1], g1);
          atomicAdd(&G[curb * NU + c0 + 2], g2);
          atomicAdd(&G[curb * NU + c0 + 3], g3);
          g0 = g1 = g2 = g3 = 0.f;
        }
        curb = b;
      }
      float hs = l_hs[row];
      int win = l_win[row];
      float wi = (float)(win >> 4), wj = (float)(win & 15);
      float dx = cx - wi;
      float ex = hs * __expf(-dx * dx * 0.125f);
      float dy0 = (float)((c0    ) & 15) - wj;
      float dy1 = (float)((c0 + 1) & 15) - wj;
      float dy2 = (float)((c0 + 2) & 15) - wj;
      float dy3 = (float)((c0 + 3) & 15) - wj;
      g0 += ex * __expf(-dy0 * dy0 * 0.125f);
      g1 += ex * __expf(-dy1 * dy1 * 0.125f);
      g2 += ex * __expf(-dy2 * dy2 * 0.125f);
      g3 += ex * __expf(-dy3 * dy3 * 0.125f);
    }
    if (curb >= 0){
      atomicAdd(&G[curb * NU + c0    ], g0);
      atomicAdd(&G[curb * NU + c0 + 1], g1);
      atomicAdd(&G[curb * NU + c0 + 2], g2);
      atomicAdd(&G[curb * NU + c0 + 3], g3);
    }
  }
}

// wave per node, 4 groups x 16 lanes; lane owns 8 features (8B fp8 rows).
// f32x2 accumulation (packed fma). outputs: xn padded bf16, h8c padded fp8, hh.
__global__ __launch_bounds__(256) void k_agg(
    const unsigned char* __restrict__ hs8, const float* __restrict__ dinv,
    const int* __restrict__ cnt, const ushort* __restrict__ col,
    const float* __restrict__ bias, ushort* __restrict__ xn,
    unsigned char* __restrict__ h8c, int cOff,
    float* __restrict__ hh){
  int lane = threadIdx.x & 63;
  int n = blockIdx.x * 4 + (threadIdx.x >> 6);
  if (n >= NN) return;
  const int g = lane >> 4, ln = lane & 15;
  const int f0 = ln * 8;
  f32x2 a0 = {0.f,0.f}, a1 = {0.f,0.f}, a2 = {0.f,0.f}, a3 = {0.f,0.f};
  if (g == 0){                     // self loop
    uint2 sv = *reinterpret_cast<const uint2*>(hs8 + (size_t)n * FD + f0);
    a0 = __builtin_amdgcn_cvt_pk_f32_fp8((int)sv.x, false);
    a1 = __builtin_amdgcn_cvt_pk_f32_fp8((int)sv.x, true );
    a2 = __builtin_amdgcn_cvt_pk_f32_fp8((int)sv.y, false);
    a3 = __builtin_amdgcn_cvt_pk_f32_fp8((int)sv.y, true );
  }
  int ne = cnt[n]; if (ne > MAXDEG) ne = MAXDEG;
  const ushort* cl = col + (size_t)n * MAXDEG;
  for (int j = 0; j < ne; j += 16){
    int i0 = j + g, i1 = j + 4 + g, i2 = j + 8 + g, i3 = j + 12 + g;
    int s0 = n, s1 = n, s2 = n, s3 = n;
    float w0 = 0.f, w1 = 0.f, w2 = 0.f, w3 = 0.f;
    if (i0 < ne){ s0 = cl[i0]; w0 = 1.f; }
    if (i1 < ne){ s1 = cl[i1]; w1 = 1.f; }
    if (i2 < ne){ s2 = cl[i2]; w2 = 1.f; }
    if (i3 < ne){ s3 = cl[i3]; w3 = 1.f; }
    uint2 r0v = *reinterpret_cast<const uint2*>(hs8 + (size_t)s0 * FD + f0);
    uint2 r1v = *reinterpret_cast<const uint2*>(hs8 + (size_t)s1 * FD + f0);
    uint2 r2v = *reinterpret_cast<const uint2*>(hs8 + (size_t)s2 * FD + f0);
    uint2 r3v = *reinterpret_cast<const uint2*>(hs8 + (size_t)s3 * FD + f0);
    f32x2 ww;
    ww = (f32x2){w0, w0};
    a0 += __builtin_amdgcn_cvt_pk_f32_fp8((int)r0v.x, false) * ww;
    a1 += __builtin_amdgcn_cvt_pk_f32_fp8((int)r0v.x, true ) * ww;
    a2 += __builtin_amdgcn_cvt_pk_f32_fp8((int)r0v.y, false) * ww;
    a3 += __builtin_amdgcn_cvt_pk_f32_fp8((int)r0v.y, true ) * ww;
    ww = (f32x2){w1, w1};
    a0 += __builtin_amdgcn_cvt_pk_f32_fp8((int)r1v.x, false) * ww;
    a1 += __builtin_amdgcn_cvt_pk_f32_fp8((int)r1v.x, true ) * ww;
    a2 += __builtin_amdgcn_cvt_pk_f32_fp8((int)r1v.y, false) * ww;
    a3 += __builtin_amdgcn_cvt_pk_f32_fp8((int)r1v.y, true ) * ww;
    ww = (f32x2){w2, w2};
    a0 += __builtin_amdgcn_cvt_pk_f32_fp8((int)r2v.x, false) * ww;
    a1 += __builtin_amdgcn_cvt_pk_f32_fp8((int)r2v.x, true ) * ww;
    a2 += __builtin_amdgcn_cvt_pk_f32_fp8((int)r2v.y, false) * ww;
    a3 += __builtin_amdgcn_cvt_pk_f32_fp8((int)r2v.y, true ) * ww;
    ww = (f32x2){w3, w3};
    a0 += __builtin_amdgcn_cvt_pk_f32_fp8((int)r3v.x, false) * ww;
    a1 += __builtin_amdgcn_cvt_pk_f32_fp8((int)r3v.x, true ) * ww;
    a2 += __builtin_amdgcn_cvt_pk_f32_fp8((int)r3v.y, false) * ww;
    a3 += __builtin_amdgcn_cvt_pk_f32_fp8((int)r3v.y, true ) * ww;
  }
  float acc[8] = {a0[0], a0[1], a1[0], a1[1], a2[0], a2[1], a3[0], a3[1]};
  #pragma unroll
  for (int k = 0; k < 8; ++k){
    acc[k] += __shfl_xor(acc[k], 16);
    acc[k] += __shfl_xor(acc[k], 32);
  }
  float di = dinv[n];
  float ssq = 0.f;
  float vv[8];
  short8 o;
  #pragma unroll
  for (int k = 0; k < 8; ++k){
    float v = acc[k] * di + bias[f0 + k];
    v = v > 0.f ? v : 0.01f * v;
    ssq += v * v;
    vv[k] = v;
    o[k] = (short)f2b(v);
  }
  if (g == 0){
    *reinterpret_cast<short8*>(xn + (size_t)n * LDA + f0) = o;
    int pa = __builtin_amdgcn_cvt_pk_fp8_f32(vv[0], vv[1], 0, false);
    pa = __builtin_amdgcn_cvt_pk_fp8_f32(vv[2], vv[3], pa, true);
    int pb = __builtin_amdgcn_cvt_pk_fp8_f32(vv[4], vv[5], 0, false);
    pb = __builtin_amdgcn_cvt_pk_fp8_f32(vv[6], vv[7], pb, true);
    uint2 pk; pk.x = (unsigned)pa; pk.y = (unsigned)pb;
    *reinterpret_cast<uint2*>(h8c + (size_t)n * LDH + cOff + f0) = pk;
    #pragma unroll
    for (int m = 1; m < 16; m <<= 1) ssq += __shfl_xor(ssq, m);
    if (ln == 0){
      if (cOff == 0) hh[n] = ssq;
      else           hh[n] += ssq;
    }
  }
}

__global__ void k_ss(const float* __restrict__ S, float* __restrict__ ss){
  int u = blockIdx.x, lane = threadIdx.x;
  const float* p = S + (size_t)u * KH + lane * 6;
  float s = 0.f;
  #pragma unroll
  for (int j = 0; j < 6; ++j){ float v = p[j]; s += v * v; }
  #pragma unroll
  for (int o = 32; o; o >>= 1) s += __shfl_down(s, o);
  if (lane == 0) ss[u] = s;
}

__global__ void k_out(const float* __restrict__ G, const float* __restrict__ lw,
                      const float* __restrict__ lb, float* __restrict__ out){
  int b = blockIdx.x, lane = threadIdx.x;
  float s = 0.f;
  #pragma unroll
  for (int j = 0; j < 4; ++j) s += G[b * NU + lane * 4 + j] * lw[lane * 4 + j];
  #pragma unroll
  for (int o = 32; o; o >>= 1) s += __shfl_down(s, o);
  if (lane == 0) out[b] = 1.f / (1.f + __expf(-(s + lb[0])));
}

extern "C" void kernel_launch(void* const* d_in, const int* in_sizes, int n_in,
                              void* d_out, int out_size, void* d_ws, size_t ws_size,
                              hipStream_t stream){
  const float* x   = (const float*)d_in[0];
  const int*   ei  = (const int*)d_in[1];
  const int*   bat = (const int*)d_in[2];
  const float* W1  = (const float*)d_in[3];
  const float* b1  = (const float*)d_in[4];
  const float* W2  = (const float*)d_in[5];
  const float* b2  = (const float*)d_in[6];
  const float* W3  = (const float*)d_in[7];
  const float* b3  = (const float*)d_in[8];
  const float* S   = (const float*)d_in[9];
  const float* lw  = (const float*)d_in[10];
  const float* lb  = (const float*)d_in[11];
  float* out = (float*)d_out;
  char* w = (char*)d_ws;

  int*      pos  = (int*)     (w + OFF_POS);
  float*    G    = (float*)   (w + OFF_G);
  int*      cnt  = (int*)     (w + OFF_CNT);
  unsigned* be   = (unsigned*)(w + OFF_BE);
  ushort*   col  = (ushort*)  (w + OFF_COL);
  float*    dinv = (float*)   (w + OFF_DINV);
  ushort*   xbf  = (ushort*)  (w + OFF_XBF);
  ushort*   xb2  = (ushort*)  (w + OFF_XB2);
  ushort*   xb3  = (ushort*)  (w + OFF_XB3);
  unsigned char* h8  = (unsigned char*)(w + OFF_H8);
  unsigned char* h8c = (unsigned char*)(w + OFF_H8C);
  float*    hh   = (float*)   (w + OFF_HH);
  ushort*   Wr   = (ushort*)  (w + OFF_WR);
  unsigned char* sbr = (unsigned char*)(w + OFF_SBR);
  float*    ss   = (float*)   (w + OFF_SS);

  hipMemsetAsync(w, 0, 66048, stream);                      // pos + G

  k_convert<<<6250, 256, 0, stream>>>(x, (ushort4*)xbf, 1600000);
  k_s8r<<<96, 256, 0, stream>>>(S, (unsigned*)sbr);
  k_twr<<<128, 128, 0, stream>>>(W1, Wr);
  k_twr<<<128, 128, 0, stream>>>(W2, Wr + 16384);
  k_twr<<<128, 128, 0, stream>>>(W3, Wr + 32768);

  k_bin<<<196, 256, 0, stream>>>(ei, pos, be);
  k_build<<<NB, 256, 0, stream>>>(pos, be, cnt, col);
  k_dinv<<<196, 256, 0, stream>>>(cnt, dinv);

  dim3 blk(256);
  // layer 1
  k_gemm<<<782, blk, 0, stream>>>(xbf, Wr, h8, NN, dinv);
  k_agg<<<12500, 256, 0, stream>>>(h8, dinv, cnt, col, b1, xb2, h8c, 0, hh);
  // layer 2
  k_gemm<<<782, blk, 0, stream>>>(xb2, Wr + 16384, h8, NN, dinv);
  k_agg<<<12500, 256, 0, stream>>>(h8, dinv, cnt, col, b2, xb3, h8c, 128, hh);
  // layer 3 (bf16 output slot reused; unused afterwards)
  k_gemm<<<782, blk, 0, stream>>>(xb3, Wr + 32768, h8, NN, dinv);
  k_agg<<<12500, 256, 0, stream>>>(h8, dinv, cnt, col, b3, xbf, h8c, 256, hh);

  k_ss<<<256, 64, 0, stream>>>(S, ss);
  // fused SOM: whole-tile fp8 GEMM + argmin + gaussian
  k_gsom<<<782, blk, 0, stream>>>(h8c, sbr, ss, hh, bat, G, NN);
  k_out<<<64, 64, 0, stream>>>(G, lw, lb, out);
}

// Round 9
// 216.712 us; speedup vs baseline: 1.2254x; 1.0740x over previous
//
#include <hip/hip_runtime.h>

#define NN 50000
#define NE 800000
#define FD 128
#define KH 384
#define NU 256
#define NG 64
#define MAXDEG 64
#define NB 98          // dst buckets of 512 nodes
#define BCAP 10240     // per-bucket capacity
#define EPB 4096       // edges per k_bin block
#define LDA 136        // padded bf16 row (272 B) for GEMM A operands
#define LDH 400        // padded fp8 row (400 B) for H-concat

typedef __attribute__((__ext_vector_type__(8))) short short8;
typedef __attribute__((__ext_vector_type__(4))) float f32x4;
typedef __attribute__((__ext_vector_type__(2))) float f32x2;

// ---- ws layout (bytes, 16B-aligned) ----
#define OFF_POS   0u           // NB int (+pad)         512     [memset]
#define OFF_G     512u         // 64*256 f32            65536   [memset]
#define OFF_CNT   66048u       // 50048 int             200192
#define OFF_BE    266240u      // NB*BCAP u32           4014080
#define OFF_COL   4280320u     // 50048*64 u16          6406144
#define OFF_DINV  10686464u    // 50048 f32             200192
#define OFF_XBF   10886656u    // 50048*272B bf16pad    13613056
#define OFF_XB2   24499712u    // 50048*272B            13613056
#define OFF_XB3   38112768u    // 50048*272B            13613056
#define OFF_H8    51725824u    // 50048*128 fp8         6406144
#define OFF_H8C   58131968u    // 50048*400B fp8pad     20019200
#define OFF_HH    78151168u    // 50048 f32             200192
#define OFF_WR    78351360u    // 3*16384 ushort        98304
#define OFF_SBR   78449664u    // 12*256*32 fp8         98304
#define OFF_SS    78547968u    // 256 f32               1024   -> total 78548992

__device__ __forceinline__ float b2f(ushort h){
  union { unsigned u; float f; } c; c.u = ((unsigned)h) << 16; return c.f;
}
__device__ __forceinline__ ushort f2b(float f){
  union { float f; unsigned u; } c; c.f = f;
  unsigned u = c.u;
  return (ushort)((u + 0x7fffu + ((u >> 16) & 1u)) >> 16);
}

// async global -> LDS: lds dest wave-uniform base; HW adds lane*16
__device__ __forceinline__ void gl16(const void* g, void* l){
  __builtin_amdgcn_global_load_lds((const __attribute__((address_space(1))) void*)g,
                                   (__attribute__((address_space(3))) void*)l, 16, 0, 0);
}

// x f32 [50000][128] -> padded bf16 rows of 136 ushorts
__global__ void k_convert(const float* __restrict__ s, ushort4* __restrict__ d, int n4){
  int i = blockIdx.x * blockDim.x + threadIdx.x;
  if (i >= n4) return;
  int r = i >> 5, q = i & 31;
  float4 v = reinterpret_cast<const float4*>(s)[i];
  ushort4 o; o.x = f2b(v.x); o.y = f2b(v.y); o.z = f2b(v.z); o.w = f2b(v.w);
  d[r * 34 + q] = o;
}

// S f32 [256][384] -> fp8 frag-contiguous: byte idx = kp*8192 + c*32 + k8*8 + b
__global__ void k_s8r(const float* __restrict__ S, unsigned* __restrict__ d){
  int tid = blockIdx.x * blockDim.x + threadIdx.x;   // 24576 = 256 * 96
  int c = tid / 96, kq = tid % 96;
  int k0 = kq * 4;
  float4 v = *reinterpret_cast<const float4*>(S + (size_t)c * KH + k0);
  int p = __builtin_amdgcn_cvt_pk_fp8_f32(v.x, v.y, 0, false);
  p = __builtin_amdgcn_cvt_pk_fp8_f32(v.z, v.w, p, true);
  int kp = k0 >> 5, k8 = (k0 >> 3) & 3;
  d[(kp * 8192 + c * 32 + k8 * 8 + (k0 & 7)) >> 2] = (unsigned)p;
}

// W f32 [128][128] (k,n) -> bf16 frag-contiguous: ushort idx = kp*4096 + n*32 + k8*8 + b
__global__ void k_twr(const float* __restrict__ W, ushort* __restrict__ Wr){
  int n = blockIdx.x, k = threadIdx.x;
  Wr[(k >> 5) * 4096 + n * 32 + ((k >> 3) & 3) * 8 + (k & 7)] = f2b(W[k * FD + n]);
}

// phase A: bin edges by dst>>9, dense bucket appends
__global__ __launch_bounds__(256) void k_bin(const int* __restrict__ ei,
                                             int* __restrict__ bucketPos,
                                             unsigned* __restrict__ be){
  __shared__ int hist[NB], base[NB], off[NB];
  int t = threadIdx.x;
  for (int i = t; i < NB; i += 256) hist[i] = 0;
  __syncthreads();
  int e0 = blockIdx.x * EPB;
  int e1 = min(e0 + EPB, NE);
  for (int e = e0 + t; e < e1; e += 256)
    atomicAdd(&hist[ei[NE + e] >> 9], 1);
  __syncthreads();
  for (int i = t; i < NB; i += 256){
    base[i] = atomicAdd(&bucketPos[i], hist[i]);
    off[i] = 0;
  }
  __syncthreads();
  for (int e = e0 + t; e < e1; e += 256){
    int d = ei[NE + e], s = ei[e];
    int b = d >> 9;
    int p = base[b] + atomicAdd(&off[b], 1);
    if (p < BCAP) be[(size_t)b * BCAP + p] = ((unsigned)(d & 511) << 16) | (unsigned)s;
  }
}

// phase B: one block per bucket; LDS degree counters; L2-local col scatter
__global__ __launch_bounds__(256) void k_build(const int* __restrict__ bucketPos,
                                               const unsigned* __restrict__ be,
                                               int* __restrict__ cnt,
                                               ushort* __restrict__ col){
  __shared__ int lcnt[512];
  int t = threadIdx.x, b = blockIdx.x;
  for (int i = t; i < 512; i += 256) lcnt[i] = 0;
  __syncthreads();
  int nE = min(bucketPos[b], BCAP);
  const unsigned* bb = be + (size_t)b * BCAP;
  for (int i = t; i < nE; i += 256){
    unsigned u = bb[i];
    int dl = u >> 16, s = u & 0xffffu;
    int pos = atomicAdd(&lcnt[dl], 1);
    if (pos < MAXDEG) col[(size_t)(b * 512 + dl) * MAXDEG + pos] = (ushort)s;
  }
  __syncthreads();
  for (int i = t; i < 512; i += 256){
    int n = b * 512 + i;
    if (n < NN) cnt[n] = lcnt[i];
  }
}

__global__ void k_dinv(const int* __restrict__ cnt, float* __restrict__ dinv){
  int i = blockIdx.x * blockDim.x + threadIdx.x;
  if (i < NN) dinv[i] = rsqrtf((float)(cnt[i] + 1));
}

// Layer GEMM: C8[M][128] = fp8( rs[r] * (A[M][128] @ W^T) )
// tile 64r x 128c, K=128 whole-tile in LDS; one barrier per block.
__global__ __launch_bounds__(256) void k_gemm(
    const ushort* __restrict__ A,              // padded rows of LDA ushorts
    const ushort* __restrict__ Wr,             // frag-contiguous [4][128][32]
    unsigned char* __restrict__ C8, int M,
    const float* __restrict__ rs){
  __shared__ __align__(16) ushort Al[64 * LDA];   // 17408 B
  const int t = threadIdx.x;
  const int lane = t & 63, w = t >> 6;
  const int wM = w >> 1, wN = w & 1;
  const int ln = lane & 15, hi = lane >> 4;
  const int mBase = blockIdx.x * 64;

  const char* Asrc = (const char*)(A + (size_t)mBase * LDA);
  #pragma unroll
  for (int j = 0; j < 4; ++j){
    int base = w * 1024 + j * 4096;
    gl16(Asrc + base + lane * 16, (char*)Al + base);
  }
  if (w == 0) gl16(Asrc + 16384 + lane * 16, (char*)Al + 16384);
  __syncthreads();

  f32x4 acc[2][4];
  #pragma unroll
  for (int i = 0; i < 2; ++i)
    #pragma unroll
    for (int j = 0; j < 4; ++j) acc[i][j] = (f32x4){0.f, 0.f, 0.f, 0.f};

  #pragma unroll
  for (int kp = 0; kp < 4; ++kp){
    short8 a[2], b[4];
    #pragma unroll
    for (int fm = 0; fm < 2; ++fm)
      a[fm] = *reinterpret_cast<const short8*>(
          (const char*)Al + (wM * 32 + fm * 16 + ln) * 272 + kp * 64 + hi * 16);
    #pragma unroll
    for (int fn = 0; fn < 4; ++fn)
      b[fn] = *reinterpret_cast<const short8*>(
          Wr + kp * 4096 + (wN * 64 + fn * 16 + ln) * 32 + hi * 8);
    #pragma unroll
    for (int fm = 0; fm < 2; ++fm)
      #pragma unroll
      for (int fn = 0; fn < 4; ++fn)
        acc[fm][fn] = __builtin_amdgcn_mfma_f32_16x16x32_bf16(a[fm], b[fn], acc[fm][fn], 0, 0, 0);
  }
  #pragma unroll
  for (int fm = 0; fm < 2; ++fm){
    int r0 = mBase + wM * 32 + fm * 16 + hi * 4;
    float rsv[4] = {0.f, 0.f, 0.f, 0.f};
    #pragma unroll
    for (int j = 0; j < 4; ++j) if (r0 + j < M) rsv[j] = rs[r0 + j];
    #pragma unroll
    for (int fn = 0; fn < 4; ++fn){
      int cg = wN * 64 + fn * 16 + ln;
      f32x4 v = acc[fm][fn];
      int p01 = __builtin_amdgcn_cvt_pk_fp8_f32(v[0] * rsv[0], v[1] * rsv[1], 0, false);
      int p23 = __builtin_amdgcn_cvt_pk_fp8_f32(v[2] * rsv[2], v[3] * rsv[3], 0, false);
      if (r0     < M) C8[(size_t)(r0    ) * FD + cg] = (unsigned char)(p01);
      if (r0 + 1 < M) C8[(size_t)(r0 + 1) * FD + cg] = (unsigned char)(p01 >> 8);
      if (r0 + 2 < M) C8[(size_t)(r0 + 2) * FD + cg] = (unsigned char)(p23);
      if (r0 + 3 < M) C8[(size_t)(r0 + 3) * FD + cg] = (unsigned char)(p23 >> 8);
    }
  }
}

// Wave-autonomous fused SOM: each wave owns 32 rows x 256 units.
// No LDS, no barriers. A direct from global (L1-resident slice),
// B frag-contiguous from L2. 391 blocks x 256 thr = 1564 waves.
__global__ __launch_bounds__(256, 2) void k_gsom(
    const unsigned char* __restrict__ A8,   // h8c padded rows of LDH
    const unsigned char* __restrict__ Br,   // Sb8r [12][256][32]
    const float* __restrict__ ss, const float* __restrict__ hh,
    const int* __restrict__ batch, float* __restrict__ G, int M){
  const int lane = threadIdx.x & 63, w = threadIdx.x >> 6;
  const int ln = lane & 15, hi = lane >> 4;
  const int gw = blockIdx.x * 4 + w;
  const int rbase = gw * 32;

  float ssr[16];
  #pragma unroll
  for (int fn = 0; fn < 16; ++fn) ssr[fn] = ss[fn * 16 + ln];

  f32x4 acc0[16], acc1[16];
  #pragma unroll
  for (int i = 0; i < 16; ++i){
    acc0[i] = (f32x4){0.f,0.f,0.f,0.f};
    acc1[i] = (f32x4){0.f,0.f,0.f,0.f};
  }

  const unsigned char* Arow0 = A8 + (size_t)(rbase + ln) * LDH + hi * 8;
  const unsigned char* Arow1 = Arow0 + 16 * LDH;
  #pragma unroll
  for (int kp = 0; kp < 12; ++kp){
    long av0 = *reinterpret_cast<const long*>(Arow0 + kp * 32);
    long av1 = *reinterpret_cast<const long*>(Arow1 + kp * 32);
    #pragma unroll
    for (int fn = 0; fn < 16; ++fn){
      long bv = *reinterpret_cast<const long*>(Br + kp * 8192 + (fn * 16 + ln) * 32 + hi * 8);
      acc0[fn] = __builtin_amdgcn_mfma_f32_16x16x32_fp8_fp8(av0, bv, acc0[fn], 0, 0, 0);
      acc1[fn] = __builtin_amdgcn_mfma_f32_16x16x32_fp8_fp8(av1, bv, acc1[fn], 0, 0, 0);
    }
  }

  // argmin per (fm, j): in-lane over 16 fn, then 16-lane shuffle reduce
  float hs_l[2][4]; int wb_l[2][4];
  #pragma unroll
  for (int fm = 0; fm < 2; ++fm){
    #pragma unroll
    for (int j = 0; j < 4; ++j){
      float mv = 3.4e38f; int mi = 0;
      #pragma unroll
      for (int fn = 0; fn < 16; ++fn){
        float v = ssr[fn] - 2.f * (fm ? acc1[fn][j] : acc0[fn][j]);
        int c = fn * 16 + ln;
        if (v < mv || (v == mv && c < mi)){ mv = v; mi = c; }
      }
      #pragma unroll
      for (int m = 1; m < 16; m <<= 1){
        float ov = __shfl_xor(mv, m);
        int   oi = __shfl_xor(mi, m);
        if (ov < mv || (ov == mv && oi < mi)){ mv = ov; mi = oi; }
      }
      int r = rbase + fm * 16 + hi * 4 + j;
      if (r < M){
        float d2 = fmaxf(hh[r] + mv, 0.f);
        hs_l[fm][j] = __expf(-sqrtf(d2));
        wb_l[fm][j] = mi | (batch[r] << 8);
      } else { hs_l[fm][j] = 0.f; wb_l[fm][j] = -1; }
    }
  }

  // gaussian over the wave's 32 rows via register broadcast (no LDS)
  float g0 = 0.f, g1 = 0.f, g2 = 0.f, g3 = 0.f;
  int curb = -1;
  int c0 = lane * 4;
  float cx = (float)(c0 >> 4);
  #pragma unroll
  for (int rr = 0; rr < 32; ++rr){
    const int fm = rr >> 4, sj = rr & 3, shi = (rr >> 2) & 3;
    int   wb = __shfl(wb_l[fm][sj], shi * 16);
    float hs = __shfl(hs_l[fm][sj], shi * 16);
    if (wb >= 0){
      int b = wb >> 8, win = wb & 255;
      if (b != curb){
        if (curb >= 0){
          atomicAdd(&G[curb * NU + c0    ], g0);
          atomicAdd(&G[curb * NU + c0 + 1], g1);
          atomicAdd(&G[curb * NU + c0 + 2], g2);
          atomicAdd(&G[curb * NU + c0 + 3], g3);
          g0 = g1 = g2 = g3 = 0.f;
        }
        curb = b;
      }
      float wi = (float)(win >> 4), wj = (float)(win & 15);
      float dx = cx - wi;
      float ex = hs * __expf(-dx * dx * 0.125f);
      float dy0 = (float)((c0    ) & 15) - wj;
      float dy1 = (float)((c0 + 1) & 15) - wj;
      float dy2 = (float)((c0 + 2) & 15) - wj;
      float dy3 = (float)((c0 + 3) & 15) - wj;
      g0 += ex * __expf(-dy0 * dy0 * 0.125f);
      g1 += ex * __expf(-dy1 * dy1 * 0.125f);
      g2 += ex * __expf(-dy2 * dy2 * 0.125f);
      g3 += ex * __expf(-dy3 * dy3 * 0.125f);
    }
  }
  if (curb >= 0){
    atomicAdd(&G[curb * NU + c0    ], g0);
    atomicAdd(&G[curb * NU + c0 + 1], g1);
    atomicAdd(&G[curb * NU + c0 + 2], g2);
    atomicAdd(&G[curb * NU + c0 + 3], g3);
  }
}

// 2 nodes per wave (independent gather chains), 4 groups x 16 lanes;
// lane owns 8 features. f32x2 packed accumulation.
__global__ __launch_bounds__(256) void k_agg(
    const unsigned char* __restrict__ hs8, const float* __restrict__ dinv,
    const int* __restrict__ cnt, const ushort* __restrict__ col,
    const float* __restrict__ bias, ushort* __restrict__ xn,
    unsigned char* __restrict__ h8c, int cOff,
    float* __restrict__ hh){
  int lane = threadIdx.x & 63;
  int wv = blockIdx.x * 4 + (threadIdx.x >> 6);
  int n0 = wv * 2;
  if (n0 >= NN) return;
  const int n1 = n0 + 1;
  const int g = lane >> 4, ln = lane & 15;
  const int f0 = ln * 8;
  f32x2 p0[4], p1[4];
  #pragma unroll
  for (int k = 0; k < 4; ++k){ p0[k] = (f32x2){0.f,0.f}; p1[k] = (f32x2){0.f,0.f}; }
  if (g == 0){                     // self loops
    uint2 sv0 = *reinterpret_cast<const uint2*>(hs8 + (size_t)n0 * FD + f0);
    uint2 sv1 = *reinterpret_cast<const uint2*>(hs8 + (size_t)n1 * FD + f0);
    p0[0] = __builtin_amdgcn_cvt_pk_f32_fp8((int)sv0.x, false);
    p0[1] = __builtin_amdgcn_cvt_pk_f32_fp8((int)sv0.x, true );
    p0[2] = __builtin_amdgcn_cvt_pk_f32_fp8((int)sv0.y, false);
    p0[3] = __builtin_amdgcn_cvt_pk_f32_fp8((int)sv0.y, true );
    p1[0] = __builtin_amdgcn_cvt_pk_f32_fp8((int)sv1.x, false);
    p1[1] = __builtin_amdgcn_cvt_pk_f32_fp8((int)sv1.x, true );
    p1[2] = __builtin_amdgcn_cvt_pk_f32_fp8((int)sv1.y, false);
    p1[3] = __builtin_amdgcn_cvt_pk_f32_fp8((int)sv1.y, true );
  }
  int ne0 = cnt[n0]; if (ne0 > MAXDEG) ne0 = MAXDEG;
  int ne1 = cnt[n1]; if (ne1 > MAXDEG) ne1 = MAXDEG;
  const ushort* cl0 = col + (size_t)n0 * MAXDEG;
  const ushort* cl1 = col + (size_t)n1 * MAXDEG;
  int nemax = ne0 > ne1 ? ne0 : ne1;
  for (int j = 0; j < nemax; j += 16){
    int s0[4], s1[4]; float w0[4], w1[4];
    #pragma unroll
    for (int q = 0; q < 4; ++q){
      int i = j + q * 4 + g;
      s0[q] = n0; w0[q] = 0.f;
      if (i < ne0){ s0[q] = cl0[i]; w0[q] = 1.f; }
      s1[q] = n1; w1[q] = 0.f;
      if (i < ne1){ s1[q] = cl1[i]; w1[q] = 1.f; }
    }
    uint2 r0[4], r1[4];
    #pragma unroll
    for (int q = 0; q < 4; ++q){
      r0[q] = *reinterpret_cast<const uint2*>(hs8 + (size_t)s0[q] * FD + f0);
      r1[q] = *reinterpret_cast<const uint2*>(hs8 + (size_t)s1[q] * FD + f0);
    }
    #pragma unroll
    for (int q = 0; q < 4; ++q){
      f32x2 ww0 = {w0[q], w0[q]};
      p0[0] += __builtin_amdgcn_cvt_pk_f32_fp8((int)r0[q].x, false) * ww0;
      p0[1] += __builtin_amdgcn_cvt_pk_f32_fp8((int)r0[q].x, true ) * ww0;
      p0[2] += __builtin_amdgcn_cvt_pk_f32_fp8((int)r0[q].y, false) * ww0;
      p0[3] += __builtin_amdgcn_cvt_pk_f32_fp8((int)r0[q].y, true ) * ww0;
      f32x2 ww1 = {w1[q], w1[q]};
      p1[0] += __builtin_amdgcn_cvt_pk_f32_fp8((int)r1[q].x, false) * ww1;
      p1[1] += __builtin_amdgcn_cvt_pk_f32_fp8((int)r1[q].x, true ) * ww1;
      p1[2] += __builtin_amdgcn_cvt_pk_f32_fp8((int)r1[q].y, false) * ww1;
      p1[3] += __builtin_amdgcn_cvt_pk_f32_fp8((int)r1[q].y, true ) * ww1;
    }
  }
  float a0[8] = {p0[0][0], p0[0][1], p0[1][0], p0[1][1], p0[2][0], p0[2][1], p0[3][0], p0[3][1]};
  float a1[8] = {p1[0][0], p1[0][1], p1[1][0], p1[1][1], p1[2][0], p1[2][1], p1[3][0], p1[3][1]};
  #pragma unroll
  for (int k = 0; k < 8; ++k){
    a0[k] += __shfl_xor(a0[k], 16); a0[k] += __shfl_xor(a0[k], 32);
    a1[k] += __shfl_xor(a1[k], 16); a1[k] += __shfl_xor(a1[k], 32);
  }
  if (g == 0){
    #pragma unroll
    for (int p = 0; p < 2; ++p){
      int n = p ? n1 : n0;
      float di = dinv[n];
      float ssq = 0.f, vv[8];
      short8 o;
      #pragma unroll
      for (int k = 0; k < 8; ++k){
        float v = (p ? a1[k] : a0[k]) * di + bias[f0 + k];
        v = v > 0.f ? v : 0.01f * v;
        ssq += v * v;
        vv[k] = v;
        o[k] = (short)f2b(v);
      }
      *reinterpret_cast<short8*>(xn + (size_t)n * LDA + f0) = o;
      int pa = __builtin_amdgcn_cvt_pk_fp8_f32(vv[0], vv[1], 0, false);
      pa = __builtin_amdgcn_cvt_pk_fp8_f32(vv[2], vv[3], pa, true);
      int pb = __builtin_amdgcn_cvt_pk_fp8_f32(vv[4], vv[5], 0, false);
      pb = __builtin_amdgcn_cvt_pk_fp8_f32(vv[6], vv[7], pb, true);
      uint2 pk; pk.x = (unsigned)pa; pk.y = (unsigned)pb;
      *reinterpret_cast<uint2*>(h8c + (size_t)n * LDH + cOff + f0) = pk;
      #pragma unroll
      for (int m = 1; m < 16; m <<= 1) ssq += __shfl_xor(ssq, m);
      if (ln == 0){
        if (cOff == 0) hh[n] = ssq;
        else           hh[n] += ssq;
      }
    }
  }
}

__global__ void k_ss(const float* __restrict__ S, float* __restrict__ ss){
  int u = blockIdx.x, lane = threadIdx.x;
  const float* p = S + (size_t)u * KH + lane * 6;
  float s = 0.f;
  #pragma unroll
  for (int j = 0; j < 6; ++j){ float v = p[j]; s += v * v; }
  #pragma unroll
  for (int o = 32; o; o >>= 1) s += __shfl_down(s, o);
  if (lane == 0) ss[u] = s;
}

__global__ void k_out(const float* __restrict__ G, const float* __restrict__ lw,
                      const float* __restrict__ lb, float* __restrict__ out){
  int b = blockIdx.x, lane = threadIdx.x;
  float s = 0.f;
  #pragma unroll
  for (int j = 0; j < 4; ++j) s += G[b * NU + lane * 4 + j] * lw[lane * 4 + j];
  #pragma unroll
  for (int o = 32; o; o >>= 1) s += __shfl_down(s, o);
  if (lane == 0) out[b] = 1.f / (1.f + __expf(-(s + lb[0])));
}

extern "C" void kernel_launch(void* const* d_in, const int* in_sizes, int n_in,
                              void* d_out, int out_size, void* d_ws, size_t ws_size,
                              hipStream_t stream){
  const float* x   = (const float*)d_in[0];
  const int*   ei  = (const int*)d_in[1];
  const int*   bat = (const int*)d_in[2];
  const float* W1  = (const float*)d_in[3];
  const float* b1  = (const float*)d_in[4];
  const float* W2  = (const float*)d_in[5];
  const float* b2  = (const float*)d_in[6];
  const float* W3  = (const float*)d_in[7];
  const float* b3  = (const float*)d_in[8];
  const float* S   = (const float*)d_in[9];
  const float* lw  = (const float*)d_in[10];
  const float* lb  = (const float*)d_in[11];
  float* out = (float*)d_out;
  char* w = (char*)d_ws;

  int*      pos  = (int*)     (w + OFF_POS);
  float*    G    = (float*)   (w + OFF_G);
  int*      cnt  = (int*)     (w + OFF_CNT);
  unsigned* be   = (unsigned*)(w + OFF_BE);
  ushort*   col  = (ushort*)  (w + OFF_COL);
  float*    dinv = (float*)   (w + OFF_DINV);
  ushort*   xbf  = (ushort*)  (w + OFF_XBF);
  ushort*   xb2  = (ushort*)  (w + OFF_XB2);
  ushort*   xb3  = (ushort*)  (w + OFF_XB3);
  unsigned char* h8  = (unsigned char*)(w + OFF_H8);
  unsigned char* h8c = (unsigned char*)(w + OFF_H8C);
  float*    hh   = (float*)   (w + OFF_HH);
  ushort*   Wr   = (ushort*)  (w + OFF_WR);
  unsigned char* sbr = (unsigned char*)(w + OFF_SBR);
  float*    ss   = (float*)   (w + OFF_SS);

  hipMemsetAsync(w, 0, 66048, stream);                      // pos + G

  k_convert<<<6250, 256, 0, stream>>>(x, (ushort4*)xbf, 1600000);
  k_s8r<<<96, 256, 0, stream>>>(S, (unsigned*)sbr);
  k_twr<<<128, 128, 0, stream>>>(W1, Wr);
  k_twr<<<128, 128, 0, stream>>>(W2, Wr + 16384);
  k_twr<<<128, 128, 0, stream>>>(W3, Wr + 32768);

  k_bin<<<196, 256, 0, stream>>>(ei, pos, be);
  k_build<<<NB, 256, 0, stream>>>(pos, be, cnt, col);
  k_dinv<<<196, 256, 0, stream>>>(cnt, dinv);

  dim3 blk(256);
  // layer 1
  k_gemm<<<782, blk, 0, stream>>>(xbf, Wr, h8, NN, dinv);
  k_agg<<<6250, 256, 0, stream>>>(h8, dinv, cnt, col, b1, xb2, h8c, 0, hh);
  // layer 2
  k_gemm<<<782, blk, 0, stream>>>(xb2, Wr + 16384, h8, NN, dinv);
  k_agg<<<6250, 256, 0, stream>>>(h8, dinv, cnt, col, b2, xb3, h8c, 128, hh);
  // layer 3 (bf16 output slot reused; unused afterwards)
  k_gemm<<<782, blk, 0, stream>>>(xb3, Wr + 32768, h8, NN, dinv);
  k_agg<<<6250, 256, 0, stream>>>(h8, dinv, cnt, col, b3, xbf, h8c, 256, hh);

  k_ss<<<256, 64, 0, stream>>>(S, ss);
  // wave-autonomous fused SOM (no LDS, no barriers)
  k_gsom<<<391, blk, 0, stream>>>(h8c, sbr, ss, hh, bat, G, NN);
  k_out<<<64, 64, 0, stream>>>(G, lw, lb, out);
}